// Round 2
// baseline (26.058 us; speedup 1.0000x reference)
//
#include <hip/hip_runtime.h>

#define BB 128
#define TT 512
#define SPLIT 8          // lag-chunks per row
#define CHUNK 64         // lags per chunk (8*64 = 512 >= 511)
#define LAG_PENALTY 0.5f

__global__ __launch_bounds__(512) void WeightedLagDenseLoss_kernel(
    const float* __restrict__ pred,
    const float* __restrict__ tgt,
    const float* __restrict__ wts,
    float* __restrict__ out)
{
    __shared__ float s_tgt[TT];
    __shared__ float s_rinv[TT];
    __shared__ float s_part[8];

    const int b = blockIdx.x;   // row
    const int s = blockIdx.y;   // lag chunk
    const int t = threadIdx.x;

    // Stage target row + 1/l table in LDS
    s_tgt[t]  = tgt[b * TT + t];
    s_rinv[t] = (t >= 1) ? (1.0f / (float)t) : 0.0f;
    __syncthreads();

    const float p = pred[b * TT + t];

    const int l0 = 1 + s * CHUNK;
    const int l1 = min(TT, l0 + CHUNK);   // s=7: 449..511 (63 lags)

    // lag_loss slice = sum_{l=l0}^{l1-1} (1/l) * (p - tgt[min(t+l, 511)])^2
    float acc0 = 0.0f, acc1 = 0.0f;
    #pragma unroll 8
    for (int l = l0; l + 1 < l1; l += 2) {
        int   i0 = min(t + l, TT - 1);
        float d0 = p - s_tgt[i0];
        acc0 = fmaf(s_rinv[l] * d0, d0, acc0);
        int   i1 = min(t + l + 1, TT - 1);
        float d1 = p - s_tgt[i1];
        acc1 = fmaf(s_rinv[l + 1] * d1, d1, acc1);
    }
    if (((l1 - l0) & 1) != 0) {   // odd trip count remainder
        int   l = l1 - 1;
        int   i = min(t + l, TT - 1);
        float d = p - s_tgt[i];
        acc0 = fmaf(s_rinv[l] * d, d, acc0);
    }
    float tot = LAG_PENALTY * (acc0 + acc1);

    if (s == SPLIT - 1) {         // add the plain MSE term exactly once
        float dm = p - s_tgt[t];
        tot = fmaf(dm, dm, tot);
    }

    // weight + exact power-of-two mean scale 1/(B*T) = 1/65536
    float v = tot * wts[b] * (1.0f / (float)(BB * TT));

    // wave64 shuffle reduction
    for (int off = 32; off > 0; off >>= 1)
        v += __shfl_down(v, off, 64);

    const int wave = t >> 6;
    if ((t & 63) == 0) s_part[wave] = v;
    __syncthreads();

    if (t == 0) {
        float sum = 0.0f;
        #pragma unroll
        for (int i = 0; i < 8; ++i) sum += s_part[i];
        atomicAdd(out, sum);
    }
}

extern "C" void kernel_launch(void* const* d_in, const int* in_sizes, int n_in,
                              void* d_out, int out_size, void* d_ws, size_t ws_size,
                              hipStream_t stream) {
    const float* pred = (const float*)d_in[0];
    const float* tgt  = (const float*)d_in[1];
    const float* wts  = (const float*)d_in[2];
    float* out = (float*)d_out;

    hipMemsetAsync(out, 0, sizeof(float), stream);
    WeightedLagDenseLoss_kernel<<<dim3(BB, SPLIT), dim3(TT), 0, stream>>>(pred, tgt, wts, out);
}

// Round 3
// 13.737 us; speedup vs baseline: 1.8969x; 1.8969x over previous
//
#include <hip/hip_runtime.h>

#define BB 128
#define TT 512
#define SPLIT 8          // lag-chunks per row
#define CHUNK 64         // lags per chunk (8*64 = 512 >= 511)
#define NPART (BB * SPLIT)
#define LAG_PENALTY 0.5f

__global__ __launch_bounds__(512) void WeightedLagDenseLoss_partial(
    const float* __restrict__ pred,
    const float* __restrict__ tgt,
    const float* __restrict__ wts,
    float* __restrict__ part)
{
    __shared__ float s_tgt[TT];
    __shared__ float s_rinv[TT];
    __shared__ float s_part[8];

    const int b = blockIdx.x;   // row
    const int s = blockIdx.y;   // lag chunk
    const int t = threadIdx.x;

    // Stage target row + 1/l table in LDS
    s_tgt[t]  = tgt[b * TT + t];
    s_rinv[t] = (t >= 1) ? (1.0f / (float)t) : 0.0f;
    __syncthreads();

    const float p = pred[b * TT + t];

    const int l0 = 1 + s * CHUNK;
    const int l1 = min(TT, l0 + CHUNK);   // s=7: 449..511 (63 lags)

    // lag_loss slice = sum_{l=l0}^{l1-1} (1/l) * (p - tgt[min(t+l, 511)])^2
    float acc0 = 0.0f, acc1 = 0.0f;
    #pragma unroll 8
    for (int l = l0; l + 1 < l1; l += 2) {
        int   i0 = min(t + l, TT - 1);
        float d0 = p - s_tgt[i0];
        acc0 = fmaf(s_rinv[l] * d0, d0, acc0);
        int   i1 = min(t + l + 1, TT - 1);
        float d1 = p - s_tgt[i1];
        acc1 = fmaf(s_rinv[l + 1] * d1, d1, acc1);
    }
    if (((l1 - l0) & 1) != 0) {   // odd trip count remainder
        int   l = l1 - 1;
        int   i = min(t + l, TT - 1);
        float d = p - s_tgt[i];
        acc0 = fmaf(s_rinv[l] * d, d, acc0);
    }
    float tot = LAG_PENALTY * (acc0 + acc1);

    if (s == SPLIT - 1) {         // add the plain MSE term exactly once
        float dm = p - s_tgt[t];
        tot = fmaf(dm, dm, tot);
    }

    // weight + exact power-of-two mean scale 1/(B*T) = 1/65536
    float v = tot * wts[b] * (1.0f / (float)(BB * TT));

    // wave64 shuffle reduction
    for (int off = 32; off > 0; off >>= 1)
        v += __shfl_down(v, off, 64);

    const int wave = t >> 6;
    if ((t & 63) == 0) s_part[wave] = v;
    __syncthreads();

    if (t == 0) {
        float sum = 0.0f;
        #pragma unroll
        for (int i = 0; i < 8; ++i) sum += s_part[i];
        part[b * SPLIT + s] = sum;   // plain store, overwritten every call
    }
}

__global__ __launch_bounds__(1024) void WeightedLagDenseLoss_reduce(
    const float* __restrict__ part,
    float* __restrict__ out)
{
    __shared__ float s_part[16];
    const int t = threadIdx.x;

    float v = part[t];             // NPART == 1024 == blockDim.x

    for (int off = 32; off > 0; off >>= 1)
        v += __shfl_down(v, off, 64);

    const int wave = t >> 6;
    if ((t & 63) == 0) s_part[wave] = v;
    __syncthreads();

    if (t == 0) {
        float sum = 0.0f;
        #pragma unroll
        for (int i = 0; i < 16; ++i) sum += s_part[i];
        out[0] = sum;              // overwrite, no zero-init needed
    }
}

extern "C" void kernel_launch(void* const* d_in, const int* in_sizes, int n_in,
                              void* d_out, int out_size, void* d_ws, size_t ws_size,
                              hipStream_t stream) {
    const float* pred = (const float*)d_in[0];
    const float* tgt  = (const float*)d_in[1];
    const float* wts  = (const float*)d_in[2];
    float* out  = (float*)d_out;
    float* part = (float*)d_ws;    // NPART floats = 4 KB of scratch

    WeightedLagDenseLoss_partial<<<dim3(BB, SPLIT), dim3(TT), 0, stream>>>(pred, tgt, wts, part);
    WeightedLagDenseLoss_reduce<<<dim3(1), dim3(NPART), 0, stream>>>(part, out);
}